// Round 10
// baseline (487.902 us; speedup 1.0000x reference)
//
#include <hip/hip_runtime.h>

#define HID 10
#define TT  2048
#define BB  4096

typedef float f2 __attribute__((ext_vector_type(2)));

static __device__ __forceinline__ f2 pkmul(f2 a, f2 b) {
    f2 d; asm("v_pk_mul_f32 %0, %1, %2" : "=v"(d) : "v"(a), "v"(b)); return d;
}
static __device__ __forceinline__ f2 pkfma(f2 a, f2 b, f2 c) {
    f2 d; asm("v_pk_fma_f32 %0, %1, %2, %3" : "=v"(d) : "v"(a), "v"(b), "v"(c)); return d;
}

__device__ __forceinline__ float fast_tanh(float x) {
    // tanh(x) = 1 - 2/(exp2(x*2*log2e) + 1); saturates correctly at +-inf
    float e = exp2f(x * 2.885390081777926814f);
    float r = __builtin_amdgcn_rcpf(e + 1.0f);
    return fmaf(-2.0f, r, 1.0f);
}

// R8 producer-consumer dataflow + TWO interleaved row-sets per wave (ILP):
//   block = 128 thr = 2 waves over 8 rows (set0 = rows b*8+g, set1 = +4).
//   wave A: layer-0 for both sets; wave B: layer-1 + fused out for both sets.
//   Each wave interleaves set0/set1 steps: the partner set's independent ops
//   fill the pk-chain, tanh, and LDS round-trip latency of the other set
//   (R8 had one chain/wave -> 47% stall; issue cadence was dep-bound).
//   Lane 10 on B rides Wout/b_out on the Whh1 pk chain -> capture = out(t-1),
//   stored with the R8-proven 1-step-lag quad carry.
// 512 blocks = 1024 waves = 1 wave/SIMD; latency hiding is intra-wave ILP.
__global__ void __launch_bounds__(128) rnn_kernel(
    const float* __restrict__ x,    const float* __restrict__ hs,
    const float* __restrict__ Wih0, const float* __restrict__ Whh0,
    const float* __restrict__ bih0, const float* __restrict__ bhh0,
    const float* __restrict__ Wih1, const float* __restrict__ Whh1,
    const float* __restrict__ bih1, const float* __restrict__ bhh1,
    const float* __restrict__ Wout, const float* __restrict__ boutp,
    float* __restrict__ out)
{
    const int tid   = threadIdx.x;
    const bool isA  = tid < 64;
    const int lane  = tid & 15;          // hidden unit slot
    const int grp   = (tid >> 4) & 3;    // row group within wave
    const int row0  = blockIdx.x * 8 + grp;
    const int row1  = row0 + 4;
    const bool act  = (lane < HID);
    const bool olane = (lane == HID);    // B: output-dot rider

    // per row: h0 ring [8][16] + h1 buf [16] = 144 floats; 8 rows.
    // bases mod 32 banks alternate {0,16} -> all accesses <=2-way (free).
    __shared__ float lds[8 * 144];
    float* ring0 = &lds[grp * 144];
    float* ring1 = &lds[(grp + 4) * 144];
    float* h1b0  = ring0 + 128;
    float* h1b1  = ring1 + 128;

    const float* x0 = x + (size_t)row0 * TT;
    const float* x1 = x + (size_t)row1 * TT;
    float*       o0 = out + (size_t)row0 * TT;
    float*       o1 = out + (size_t)row1 * TT;

    // ---- role state (weights shared across both sets) ----
    f2 whh0p[5]; float wih0i = 0.f, bc = 0.f;     // A
    f2 wih1p[5], whh1p[5];                         // B
    f2 H_0[5], H_1[5];   // A: h0 broadcast per set | B: h1 broadcast per set
    float4 xq0 = make_float4(0,0,0,0), xq1 = make_float4(0,0,0,0);
    float own0 = 0.f, own1 = 0.f;                  // own-unit state per set
    float P10=0.f,P20=0.f,P30=0.f, P11=0.f,P21=0.f,P31=0.f;  // B store carry

    if (isA) {
        #pragma unroll
        for (int j = 0; j < 5; ++j)
            whh0p[j] = act ? f2{Whh0[lane*HID + 2*j], Whh0[lane*HID + 2*j+1]}
                           : f2{0.f, 0.f};
        wih0i = act ? Wih0[lane] : 0.f;
        bc    = act ? (bih0[lane] + bhh0[lane]) : 0.f;
        #pragma unroll
        for (int j = 0; j < 5; ++j) {
            H_0[j] = f2{hs[row0*HID + 2*j], hs[row0*HID + 2*j+1]};
            H_1[j] = f2{hs[row1*HID + 2*j], hs[row1*HID + 2*j+1]};
        }
        xq0 = *(const float4*)(x0);
        xq1 = *(const float4*)(x1);
    } else {
        #pragma unroll
        for (int j = 0; j < 5; ++j) {
            wih1p[j] = act ? f2{Wih1[lane*HID + 2*j], Wih1[lane*HID + 2*j+1]}
                           : f2{0.f, 0.f};
            whh1p[j] = act ? f2{Whh1[lane*HID + 2*j], Whh1[lane*HID + 2*j+1]}
                     : (olane ? f2{Wout[2*j], Wout[2*j+1]} : f2{0.f, 0.f});
        }
        bc = act ? (bih1[lane] + bhh1[lane]) : (olane ? boutp[0] : 0.f);
        #pragma unroll
        for (int j = 0; j < 5; ++j) {
            H_0[j] = f2{hs[BB*HID + row0*HID + 2*j], hs[BB*HID + row0*HID + 2*j+1]};
            H_1[j] = f2{hs[BB*HID + row1*HID + 2*j], hs[BB*HID + row1*HID + 2*j+1]};
        }
    }

// A: one layer-0 step for one set. Write own h0, read back full broadcast.
#define ASTEP(HV, RING, XV, OWN) do {                                    \
    f2 acc = pkmul(whh0p[0], HV[0]);                                     \
    acc = pkfma(whh0p[1], HV[1], acc);                                   \
    acc = pkfma(whh0p[2], HV[2], acc);                                   \
    acc = pkfma(whh0p[3], HV[3], acc);                                   \
    acc = pkfma(whh0p[4], HV[4], acc);                                   \
    const float a0 = fmaf((XV), wih0i, bc);                              \
    OWN = fast_tanh((a0 + acc.x) + acc.y);                               \
    (RING)[slot + lane] = OWN;                                           \
    __builtin_amdgcn_wave_barrier();                                     \
    const float* _rb = (RING) + slot;                                    \
    const float4 _r0 = *(const float4*)(_rb);                            \
    const float4 _r1 = *(const float4*)(_rb + 4);                        \
    const f2     _r2 = *(const f2*)(_rb + 8);                            \
    HV[0] = f2{_r0.x, _r0.y}; HV[1] = f2{_r0.z, _r0.w};                  \
    HV[2] = f2{_r1.x, _r1.y}; HV[3] = f2{_r1.z, _r1.w};                  \
    HV[4] = _r2;                                                         \
} while (0)

// B: one layer-1 step for one set, h0(t) pre-read in U0/U1/U2 regs.
#define BSTEP(HV, H1B, U0, U1, U2, OWN, SDST) do {                       \
    f2 qc = pkmul(whh1p[0], HV[0]);                                      \
    qc = pkfma(whh1p[1], HV[1], qc);                                     \
    qc = pkfma(whh1p[2], HV[2], qc);                                     \
    qc = pkfma(whh1p[3], HV[3], qc);                                     \
    qc = pkfma(whh1p[4], HV[4], qc);                                     \
    f2 pc = pkmul(wih1p[0], f2{U0.x, U0.y});                             \
    pc = pkfma(wih1p[1], f2{U0.z, U0.w}, pc);                            \
    pc = pkfma(wih1p[2], f2{U1.x, U1.y}, pc);                            \
    pc = pkfma(wih1p[3], f2{U1.z, U1.w}, pc);                            \
    pc = pkfma(wih1p[4], U2, pc);                                        \
    const float _s1 = ((bc + qc.x) + qc.y) + (pc.x + pc.y);              \
    SDST = _s1;                          /* lane10: out(t-1) */          \
    OWN = fast_tanh(_s1);                                                \
    (H1B)[lane] = OWN;                                                   \
    __builtin_amdgcn_wave_barrier();                                     \
    const float4 _q0 = *(const float4*)(H1B);                            \
    const float4 _q1 = *(const float4*)((H1B) + 4);                      \
    const f2     _q2 = *(const f2*)((H1B) + 8);                          \
    HV[0] = f2{_q0.x, _q0.y}; HV[1] = f2{_q0.z, _q0.w};                  \
    HV[2] = f2{_q1.x, _q1.y}; HV[3] = f2{_q1.z, _q1.w};                  \
    HV[4] = _q2;                                                         \
} while (0)

    const int M = TT / 4;
    for (int m = 0; m <= M; ++m) {
        if (isA) {
            if (m < M) {
                const int mn = (m + 1 < M) ? m + 1 : M - 1;
                const float4 xn0 = *(const float4*)(x0 + 4 * mn);
                const float4 xn1 = *(const float4*)(x1 + 4 * mn);
                const float xs0[4] = {xq0.x, xq0.y, xq0.z, xq0.w};
                const float xs1[4] = {xq1.x, xq1.y, xq1.z, xq1.w};
                #pragma unroll
                for (int k = 0; k < 4; ++k) {
                    const int slot = ((4 * m + k) & 7) * 16;
                    ASTEP(H_0, ring0, xs0[k], own0);
                    ASTEP(H_1, ring1, xs1[k], own1);
                }
                xq0 = xn0; xq1 = xn1;
            }
        } else {
            if (m > 0) {
                const int tb = 4 * (m - 1);
                float c00=0.f,c10=0.f,c20=0.f,c30=0.f;
                float c01=0.f,c11=0.f,c21=0.f,c31=0.f;
                #pragma unroll
                for (int k = 0; k < 4; ++k) {
                    const int slot = ((tb + k) & 7) * 16;
                    const float* rb0 = ring0 + slot;
                    const float* rb1 = ring1 + slot;
                    const float4 u0 = *(const float4*)(rb0);
                    const float4 u1 = *(const float4*)(rb0 + 4);
                    const f2     u2 = *(const f2*)(rb0 + 8);
                    const float4 v0 = *(const float4*)(rb1);
                    const float4 v1 = *(const float4*)(rb1 + 4);
                    const f2     v2 = *(const f2*)(rb1 + 8);
                    float s0d, s1d;
                    BSTEP(H_0, h1b0, u0, u1, u2, own0, s0d);
                    BSTEP(H_1, h1b1, v0, v1, v2, own1, s1d);
                    if      (k == 0) { c00 = s0d; c01 = s1d; }
                    else if (k == 1) { c10 = s0d; c11 = s1d; }
                    else if (k == 2) { c20 = s0d; c21 = s1d; }
                    else             { c30 = s0d; c31 = s1d; }
                }
                // c_k = out(tb+k-1): store previous aligned quad, carry rest
                if (olane && m >= 2) {
                    *(float4*)(o0 + tb - 4) = make_float4(P10, P20, P30, c00);
                    *(float4*)(o1 + tb - 4) = make_float4(P11, P21, P31, c01);
                }
                P10 = c10; P20 = c20; P30 = c30;
                P11 = c11; P21 = c21; P31 = c31;
            }
        }
        __syncthreads();
    }

    if (!isA) {
        // epilogue: out(2047) = rider dot with final H1 = h1(2047)
        f2 e0 = pkmul(whh1p[0], H_0[0]);
        e0 = pkfma(whh1p[1], H_0[1], e0);
        e0 = pkfma(whh1p[2], H_0[2], e0);
        e0 = pkfma(whh1p[3], H_0[3], e0);
        e0 = pkfma(whh1p[4], H_0[4], e0);
        f2 e1 = pkmul(whh1p[0], H_1[0]);
        e1 = pkfma(whh1p[1], H_1[1], e1);
        e1 = pkfma(whh1p[2], H_1[2], e1);
        e1 = pkfma(whh1p[3], H_1[3], e1);
        e1 = pkfma(whh1p[4], H_1[4], e1);
        if (olane) {
            *(float4*)(o0 + TT - 4) = make_float4(P10, P20, P30, (bc + e0.x) + e0.y);
            *(float4*)(o1 + TT - 4) = make_float4(P11, P21, P31, (bc + e1.x) + e1.y);
        }
    }

    // final hidden state: [2, B, H] appended after B*T outputs
    if (isA) {
        if (act) {
            out[(size_t)BB*TT + (size_t)row0*HID + lane] = own0;
            out[(size_t)BB*TT + (size_t)row1*HID + lane] = own1;
        }
    } else {
        if (act) {
            out[(size_t)BB*TT + (size_t)BB*HID + (size_t)row0*HID + lane] = own0;
            out[(size_t)BB*TT + (size_t)BB*HID + (size_t)row1*HID + lane] = own1;
        }
    }
#undef ASTEP
#undef BSTEP
}

extern "C" void kernel_launch(void* const* d_in, const int* in_sizes, int n_in,
                              void* d_out, int out_size, void* d_ws, size_t ws_size,
                              hipStream_t stream) {
    const float* x    = (const float*)d_in[0];
    const float* hs   = (const float*)d_in[1];
    const float* Wih0 = (const float*)d_in[2];
    const float* Whh0 = (const float*)d_in[3];
    const float* bih0 = (const float*)d_in[4];
    const float* bhh0 = (const float*)d_in[5];
    const float* Wih1 = (const float*)d_in[6];
    const float* Whh1 = (const float*)d_in[7];
    const float* bih1 = (const float*)d_in[8];
    const float* bhh1 = (const float*)d_in[9];
    const float* Wout = (const float*)d_in[10];
    const float* bout = (const float*)d_in[11];
    float* out = (float*)d_out;

    dim3 grid(BB / 8), block(128);
    hipLaunchKernelGGL(rnn_kernel, grid, block, 0, stream,
        x, hs, Wih0, Whh0, bih0, bhh0, Wih1, Whh1, bih1, bhh1, Wout, bout, out);
}

// Round 11
// 293.982 us; speedup vs baseline: 1.6596x; 1.6596x over previous
//
#include <hip/hip_runtime.h>

#define HID 10
#define TT  2048
#define BB  4096

typedef float f2 __attribute__((ext_vector_type(2)));

static __device__ __forceinline__ f2 pkmul(f2 a, f2 b) {
    f2 d; asm("v_pk_mul_f32 %0, %1, %2" : "=v"(d) : "v"(a), "v"(b)); return d;
}
static __device__ __forceinline__ f2 pkfma(f2 a, f2 b, f2 c) {
    f2 d; asm("v_pk_fma_f32 %0, %1, %2, %3" : "=v"(d) : "v"(a), "v"(b), "v"(c)); return d;
}

__device__ __forceinline__ float fast_tanh(float x) {
    // tanh(x) = 1 - 2/(exp2(x*2*log2e) + 1); saturates correctly at +-inf
    float e = exp2f(x * 2.885390081777926814f);
    float r = __builtin_amdgcn_rcpf(e + 1.0f);
    return fmaf(-2.0f, r, 1.0f);
}

// THREE-wave specialization, 4 rows/block (192 thr = 3 waves, 3 waves/SIMD):
//   wave A  (role 0): layer-0 recurrence; publishes h0(t) into 8-slot ring.
//   wave B1 (role 1): u(t) = Wih1.h0(t) + b1 -- pure feed-forward over the
//                     lagged h0-ring, NO serial chain (never latency-bound);
//                     publishes scalar u per (step,unit) into the u-ring.
//                     Lane 10 gets ub = b_out, wih1p = 0.
//   wave B2 (role 2): h1 recurrence: s1 = u + Whh1.h1(t-1); tanh; broadcast.
//                     Lane 10 rides Wout on the Whh1 chain -> s1 = out(t-1);
//                     stored with the R8-proven 1-step-lag quad carry.
// Pipeline: A@m, B1@m-1, B2@m-2; one __syncthreads per 4 steps.
// 3072 waves = 3/SIMD of NON-duplicated work: stalls of the two chained
// waves (A, B2) hide under B1 + each other (R8 had only 2 chains/SIMD).
__global__ void __launch_bounds__(192) rnn_kernel(
    const float* __restrict__ x,    const float* __restrict__ hs,
    const float* __restrict__ Wih0, const float* __restrict__ Whh0,
    const float* __restrict__ bih0, const float* __restrict__ bhh0,
    const float* __restrict__ Wih1, const float* __restrict__ Whh1,
    const float* __restrict__ bih1, const float* __restrict__ bhh1,
    const float* __restrict__ Wout, const float* __restrict__ boutp,
    float* __restrict__ out)
{
    const int tid   = threadIdx.x;
    const int role  = tid >> 6;          // 0=A, 1=B1, 2=B2
    const int lane  = tid & 15;          // hidden unit slot
    const int grp   = (tid >> 4) & 3;    // row within block
    const int row   = blockIdx.x * 4 + grp;
    const bool act  = (lane < HID);
    const bool olane = (lane == HID);

    // per row (stride 272 floats == 16 mod 32 banks -> <=2-way, free):
    //   h0 ring [8][16] | u ring [8][16] | h1 buf [16]
    __shared__ float lds[4 * 272];
    float* h0r = &lds[grp * 272];
    float* ur  = h0r + 128;
    float* h1b = h0r + 256;

    const float* xrow = x   + (size_t)row * TT;
    float*       orow = out + (size_t)row * TT;

    // ---- role state ----
    f2 w0p[5]; float wih0i = 0.f, b0c = 0.f; f2 H0[5];   // A
    float4 xq = make_float4(0,0,0,0);
    f2 w1p[5]; float ub = 0.f;                            // B1
    f2 w2p[5]; f2 H1[5]; float bo = 0.f;                  // B2
    float P1 = 0.f, P2 = 0.f, P3 = 0.f;
    float h0own = 0.f, h1own = 0.f;

    if (role == 0) {
        #pragma unroll
        for (int j = 0; j < 5; ++j)
            w0p[j] = act ? f2{Whh0[lane*HID + 2*j], Whh0[lane*HID + 2*j+1]}
                         : f2{0.f, 0.f};
        wih0i = act ? Wih0[lane] : 0.f;
        b0c   = act ? (bih0[lane] + bhh0[lane]) : 0.f;
        #pragma unroll
        for (int j = 0; j < 5; ++j)
            H0[j] = f2{hs[row*HID + 2*j], hs[row*HID + 2*j+1]};
        xq = *(const float4*)(xrow);
    } else if (role == 1) {
        #pragma unroll
        for (int j = 0; j < 5; ++j)
            w1p[j] = act ? f2{Wih1[lane*HID + 2*j], Wih1[lane*HID + 2*j+1]}
                         : f2{0.f, 0.f};
        ub = act ? (bih1[lane] + bhh1[lane]) : (olane ? boutp[0] : 0.f);
    } else {
        #pragma unroll
        for (int j = 0; j < 5; ++j)
            w2p[j] = act ? f2{Whh1[lane*HID + 2*j], Whh1[lane*HID + 2*j+1]}
                   : (olane ? f2{Wout[2*j], Wout[2*j+1]} : f2{0.f, 0.f});
        #pragma unroll
        for (int j = 0; j < 5; ++j)
            H1[j] = f2{hs[BB*HID + row*HID + 2*j], hs[BB*HID + row*HID + 2*j+1]};
        bo = boutp[0];
    }

    const int M = TT / 4;
    for (int m = 0; m <= M + 1; ++m) {
        if (role == 0) {
            if (m < M) {
                const int mn = (m + 1 < M) ? m + 1 : M - 1;
                const float4 xn = *(const float4*)(xrow + 4 * mn);
                const float xs[4] = {xq.x, xq.y, xq.z, xq.w};
                #pragma unroll
                for (int k = 0; k < 4; ++k) {
                    const int slot = ((4 * m + k) & 7) * 16;
                    f2 acc = pkmul(w0p[0], H0[0]);
                    acc = pkfma(w0p[1], H0[1], acc);
                    acc = pkfma(w0p[2], H0[2], acc);
                    acc = pkfma(w0p[3], H0[3], acc);
                    acc = pkfma(w0p[4], H0[4], acc);
                    const float a0 = fmaf(xs[k], wih0i, b0c);
                    h0own = fast_tanh((a0 + acc.x) + acc.y);
                    h0r[slot + lane] = h0own;
                    __builtin_amdgcn_wave_barrier();
                    const float* rb = h0r + slot;
                    const float4 r0 = *(const float4*)(rb);
                    const float4 r1 = *(const float4*)(rb + 4);
                    const f2     r2 = *(const f2*)(rb + 8);
                    H0[0] = f2{r0.x, r0.y}; H0[1] = f2{r0.z, r0.w};
                    H0[2] = f2{r1.x, r1.y}; H0[3] = f2{r1.z, r1.w};
                    H0[4] = r2;
                }
                xq = xn;
            }
        } else if (role == 1) {
            if (m >= 1 && m <= M) {
                const int tb = 4 * (m - 1);
                // phase 1: read all 4 slots' h0 (12 LDS reads, no chain)
                float4 a[4], b[4]; f2 c[4];
                #pragma unroll
                for (int k = 0; k < 4; ++k) {
                    const float* rb = h0r + ((tb + k) & 7) * 16;
                    a[k] = *(const float4*)(rb);
                    b[k] = *(const float4*)(rb + 4);
                    c[k] = *(const f2*)(rb + 8);
                }
                // phase 2: 4 independent pk chains + scalar u writes
                #pragma unroll
                for (int k = 0; k < 4; ++k) {
                    f2 pc = pkmul(w1p[0], f2{a[k].x, a[k].y});
                    pc = pkfma(w1p[1], f2{a[k].z, a[k].w}, pc);
                    pc = pkfma(w1p[2], f2{b[k].x, b[k].y}, pc);
                    pc = pkfma(w1p[3], f2{b[k].z, b[k].w}, pc);
                    pc = pkfma(w1p[4], c[k], pc);
                    ur[((tb + k) & 7) * 16 + lane] = (ub + pc.x) + pc.y;
                }
            }
        } else {
            if (m >= 2 && m <= M + 1) {
                const int tb = 4 * (m - 2);
                // prefetch the 4 scalar u's (lagged ring, latency-free)
                float uo[4];
                #pragma unroll
                for (int k = 0; k < 4; ++k)
                    uo[k] = ur[((tb + k) & 7) * 16 + lane];
                float c0 = 0.f, c1 = 0.f, c2 = 0.f, c3 = 0.f;
                #pragma unroll
                for (int k = 0; k < 4; ++k) {
                    f2 qc = pkmul(w2p[0], H1[0]);
                    qc = pkfma(w2p[1], H1[1], qc);
                    qc = pkfma(w2p[2], H1[2], qc);
                    qc = pkfma(w2p[3], H1[3], qc);
                    qc = pkfma(w2p[4], H1[4], qc);
                    const float s1 = (uo[k] + qc.x) + qc.y;  // lane10: out(t-1)
                    if      (k == 0) c0 = s1;
                    else if (k == 1) c1 = s1;
                    else if (k == 2) c2 = s1;
                    else             c3 = s1;
                    h1own = fast_tanh(s1);
                    h1b[lane] = h1own;
                    __builtin_amdgcn_wave_barrier();
                    const float4 q0 = *(const float4*)(h1b);
                    const float4 q1 = *(const float4*)(h1b + 4);
                    const f2     q2 = *(const f2*)(h1b + 8);
                    H1[0] = f2{q0.x, q0.y}; H1[1] = f2{q0.z, q0.w};
                    H1[2] = f2{q1.x, q1.y}; H1[3] = f2{q1.z, q1.w};
                    H1[4] = q2;
                }
                // c_k = out(tb+k-1): store previous aligned quad, carry rest
                if (olane && m >= 3)
                    *(float4*)(orow + tb - 4) = make_float4(P1, P2, P3, c0);
                P1 = c1; P2 = c2; P3 = c3;
            }
        }
        __syncthreads();
    }

    if (role == 2) {
        // epilogue: out(2047) = bout + Wout . h1(2047) (rider weights in w2p)
        f2 e = pkmul(w2p[0], H1[0]);
        e = pkfma(w2p[1], H1[1], e);
        e = pkfma(w2p[2], H1[2], e);
        e = pkfma(w2p[3], H1[3], e);
        e = pkfma(w2p[4], H1[4], e);
        if (olane)
            *(float4*)(orow + TT - 4) = make_float4(P1, P2, P3, (bo + e.x) + e.y);
        if (act)
            out[(size_t)BB*TT + (size_t)BB*HID + (size_t)row*HID + lane] = h1own;
    }
    if (role == 0 && act)
        out[(size_t)BB*TT + (size_t)row*HID + lane] = h0own;
}

extern "C" void kernel_launch(void* const* d_in, const int* in_sizes, int n_in,
                              void* d_out, int out_size, void* d_ws, size_t ws_size,
                              hipStream_t stream) {
    const float* x    = (const float*)d_in[0];
    const float* hs   = (const float*)d_in[1];
    const float* Wih0 = (const float*)d_in[2];
    const float* Whh0 = (const float*)d_in[3];
    const float* bih0 = (const float*)d_in[4];
    const float* bhh0 = (const float*)d_in[5];
    const float* Wih1 = (const float*)d_in[6];
    const float* Whh1 = (const float*)d_in[7];
    const float* bih1 = (const float*)d_in[8];
    const float* bhh1 = (const float*)d_in[9];
    const float* Wout = (const float*)d_in[10];
    const float* bout = (const float*)d_in[11];
    float* out = (float*)d_out;

    dim3 grid(BB / 4), block(192);
    hipLaunchKernelGGL(rnn_kernel, grid, block, 0, stream,
        x, hs, Wih0, Whh0, bih0, bhh0, Wih1, Whh1, bih1, bhh1, Wout, bout, out);
}